// Round 1
// 380.892 us; speedup vs baseline: 1.0003x; 1.0003x over previous
//
#include <hip/hip_runtime.h>
#include <cmath>

// ---------------------------------------------------------------------------
// Round 12: GEMM ported to the 256^2 8-phase template (T2+T3+T4+T5):
//   - 256x256 tile, BK=64, 8 waves (2Mx4N), 512 thr, acc[8][4], 128KB LDS dbuf
//   - per K-tile 4 phases: {ds_read || stage-issue; s_barrier; lgkmcnt(0);
//     setprio(1) 16xMFMA setprio(0); s_barrier}; raw asm barriers (no drain)
//   - counted s_waitcnt vmcnt(8) ONCE per K-tile (phase 4): next tile's 8
//     loads stay in flight across barriers (B halves staged ph3, A ph4 --
//     slots provably free: B read ph1-2, A read ph1,3)
//   - same XOR-octet swizzle both sides (source pre-swizzle + read swizzle),
//     same MFMA K order -> bitwise-identical acc vs round 11
//   - XCD supertile 8bm x 4bn, bmi fastest: per-XCD = 1 A-panel + 4 B-panels
//     = 2.5MB < 4MB L2; A-panels persist across 8 consecutive supertiles
// Arena (inside attention output region): slot r (16 KB) =
//   [ G-bf16 row r : 8 KB | input bf16 chunks 4r..4r+3 : 8 KB ]
// chunk order: 0..N-1 step, N..N+M-1 modal, N+M..N+2M-1 negs.
// ---------------------------------------------------------------------------

#define WAVE 64

typedef __bf16 bf16x8_t __attribute__((ext_vector_type(8)));
typedef __bf16 bf16x4_t __attribute__((ext_vector_type(4)));
typedef float f32x4_t __attribute__((ext_vector_type(4)));

__device__ __forceinline__ float wave_reduce_sum(float v) {
#pragma unroll
    for (int o = 32; o > 0; o >>= 1) v += __shfl_down(v, o, WAVE);
    return v;
}
__device__ __forceinline__ float wave_reduce_max(float v) {
#pragma unroll
    for (int o = 32; o > 0; o >>= 1) v = fmaxf(v, __shfl_down(v, o, WAVE));
    return v;
}
__device__ __forceinline__ float wave_reduce_min(float v) {
#pragma unroll
    for (int o = 32; o > 0; o >>= 1) v = fminf(v, __shfl_down(v, o, WAVE));
    return v;
}

// monotone float <-> uint map for atomicMax on floats of any sign
__device__ __forceinline__ unsigned enc_f(float f) {
    unsigned u = __float_as_uint(f);
    return (u & 0x80000000u) ? ~u : (u | 0x80000000u);
}
__device__ __forceinline__ float dec_f(unsigned e) {
    unsigned u = (e & 0x80000000u) ? (e & 0x7fffffffu) : ~e;
    return __uint_as_float(u);
}

// ---------------- convert fp32 -> bf16 chunks + inverse norms --------------
// one row per WAVE (4 rows/block), no block barriers.
__global__ __launch_bounds__(256)
void convert_norms_kernel(const float* __restrict__ step,
                          const float* __restrict__ modal,
                          const float* __restrict__ negs,
                          char* __restrict__ arena,
                          float* __restrict__ ina, float* __restrict__ inb,
                          float* __restrict__ inn,
                          unsigned* __restrict__ negmax_u, int N, int M) {
    const int tid = threadIdx.x, lane = tid & 63, wv = tid >> 6;
    const int b = blockIdx.x * 4 + wv;
    const float* src;
    if (b < N)          src = step  + (size_t)b * 1024;
    else if (b < N + M) src = modal + (size_t)(b - N) * 1024;
    else                src = negs  + (size_t)(b - N - M) * 1024;

    char* cb = arena + (((size_t)(b >> 2)) << 14) + ((size_t)(b & 3) << 11) + 8192;
    float s = 0.0f;
#pragma unroll
    for (int q = 0; q < 4; q++) {
        const int idx = lane + q * 64;
        const float4 v = ((const float4*)src)[idx];
        bf16x4_t o;
        o[0] = (__bf16)v.x; o[1] = (__bf16)v.y;
        o[2] = (__bf16)v.z; o[3] = (__bf16)v.w;
        *(bf16x4_t*)(cb + (size_t)idx * 8) = o;
        s += v.x * v.x + v.y * v.y + v.z * v.z + v.w * v.w;
    }
    s = wave_reduce_sum(s);
    if (lane == 0) {
        const float inv = 1.0f / fmaxf(sqrtf(s), 1e-8f);
        if (b < N)          { ina[b] = inv; negmax_u[b] = 0u; }
        else if (b < N + M) inb[b - N] = inv;
        else                inn[b - N - M] = inv;
    }
}

// ---------------- fused bf16 MFMA GEMM, 256^2 8-phase ----------------------
#define GLD16(g, l)                                                       \
    __builtin_amdgcn_global_load_lds(                                     \
        (const __attribute__((address_space(1))) void*)(g),               \
        (__attribute__((address_space(3))) void*)(l), 16, 0, 0)

#define BAR()   asm volatile("s_barrier" ::: "memory")
#define LGKM0() asm volatile("s_waitcnt lgkmcnt(0)" ::: "memory")
#define VMW(n)  asm volatile("s_waitcnt vmcnt(" #n ")" ::: "memory")

#define STAGE_A(Ab, kt)                                                   \
    _Pragma("unroll")                                                     \
    for (int h = 0; h < 2; h++)                                           \
    _Pragma("unroll")                                                     \
      for (int c = 0; c < 2; c++)                                         \
        GLD16(arena + srcA[h][c] + (size_t)(kt) * 128,                    \
              (Ab) + h * 8192 + c * 4096 + w * 512);

#define STAGE_B(Bb, kt)                                                   \
    _Pragma("unroll")                                                     \
    for (int h = 0; h < 2; h++)                                           \
    _Pragma("unroll")                                                     \
      for (int c = 0; c < 2; c++)                                         \
        GLD16(arena + srcB[h][c] + (size_t)(kt) * 128,                    \
              (Bb) + h * 8192 + c * 4096 + w * 512);

#define READ_A(g, Ab)                                                     \
    _Pragma("unroll")                                                     \
    for (int ii = 0; ii < 4; ii++)                                        \
    _Pragma("unroll")                                                     \
      for (int kk = 0; kk < 2; kk++)                                      \
        af[ii][kk] = *(const bf16x8_t*)&(Ab)[arow0 + (g) * 4096 +         \
                                             ii * 1024 + koff[kk]];

#define READ_B(j0, dst, Bb)                                               \
    _Pragma("unroll")                                                     \
    for (int jj = 0; jj < 2; jj++)                                        \
    _Pragma("unroll")                                                     \
      for (int kk = 0; kk < 2; kk++)                                      \
        dst[jj][kk] = *(const bf16x8_t*)&(Bb)[brow0 + ((j0) + jj) * 1024 +\
                                              koff[kk]];

#define MFMA_Q(i0, j0, bsrc)                                              \
    __builtin_amdgcn_s_setprio(1);                                        \
    _Pragma("unroll")                                                     \
    for (int kk = 0; kk < 2; kk++)                                        \
    _Pragma("unroll")                                                     \
      for (int ii = 0; ii < 4; ii++)                                      \
      _Pragma("unroll")                                                   \
        for (int jj = 0; jj < 2; jj++)                                    \
          acc[(i0) + ii][(j0) + jj] =                                     \
              __builtin_amdgcn_mfma_f32_16x16x32_bf16(                    \
                  af[ii][kk], bsrc[jj][kk], acc[(i0) + ii][(j0) + jj],    \
                  0, 0, 0);                                               \
    __builtin_amdgcn_s_setprio(0);

// one K-tile = 4 phases, 16 MFMA each; counted vmcnt once at phase 4
#define TILE(Ab, Bb, ktpre, pre)                                          \
    /* phase 1 */                                                         \
    READ_A(0, Ab);                                                        \
    READ_B(0, bf01, Bb);                                                  \
    BAR(); LGKM0();                                                       \
    MFMA_Q(0, 0, bf01);                                                   \
    BAR();                                                                \
    /* phase 2 */                                                         \
    READ_B(2, bf23, Bb);                                                  \
    BAR(); LGKM0();                                                       \
    MFMA_Q(0, 2, bf23);                                                   \
    BAR();                                                                \
    /* phase 3: B slots of this buffer free (read ph1-2) -> stage next */ \
    READ_A(1, Ab);                                                        \
    if (pre) { STAGE_B(Bb, ktpre); }                                      \
    BAR(); LGKM0();                                                       \
    MFMA_Q(4, 0, bf01);                                                   \
    BAR();                                                                \
    /* phase 4: A slots free (read ph1,3) -> stage next; counted vmcnt */ \
    if (pre) { STAGE_A(Ab, ktpre); }                                      \
    BAR();                                                                \
    MFMA_Q(4, 2, bf23);                                                   \
    if (pre) { VMW(8); } else { VMW(0); }                                 \
    BAR();

__global__ __launch_bounds__(512, 2)
void gemm_fused_kernel(char* __restrict__ arena, int N, int M,
                       const float* __restrict__ inv_nn,
                       unsigned* __restrict__ negmax_u) {
    __shared__ __bf16 As[2][256 * 64];   // 2 x 32 KB
    __shared__ __bf16 Bs[2][256 * 64];   // 2 x 32 KB  (total 128 KB)

    // supertile: 8 bm x 4 bn, bmi fastest -> XCD (lin%8) pinned to one bmi
    const int lin = blockIdx.x;
    const int sid = lin >> 5, qq = lin & 31;
    const int bmi = qq & 7, bni = qq >> 3;
    const int bmg = sid >> 3, stn = sid & 7;
    const int bm = (bmg * 8 + bmi) << 8;
    const int bn = (stn * 4 + bni) << 8;

    const int t = threadIdx.x, w = t >> 6, lane = t & 63;
    const int lane16 = lane & 15, lq = lane >> 4;
    const int wm = w >> 2, wn = w & 3;          // 2 M-waves x 4 N-waves

    // ---- staging source offsets (bytes from arena; xor-swizzled octet) ----
    const int l3 = lane >> 3, ol = lane & 7;
    const int og = ol ^ l3;                      // (grow&7)==l3 for all rows
    unsigned srcA[2][2], srcB[2][2];
#pragma unroll
    for (int h = 0; h < 2; h++)
#pragma unroll
      for (int c = 0; c < 2; c++) {
        const int ga = bm + h * 128 + c * 64 + w * 8 + l3;
        srcA[h][c] = ((unsigned)(ga >> 2) << 14) + ((unsigned)(ga & 3) << 11)
                     + 8192u + (unsigned)og * 16u;
        const int gb = N + bn + h * 128 + c * 64 + w * 8 + l3;
        srcB[h][c] = ((unsigned)(gb >> 2) << 14) + ((unsigned)(gb & 3) << 11)
                     + 8192u + (unsigned)og * 16u;
      }

    // ---- fragment read offsets (swizzled octet, elements) ----
    const int sxr = lane16 & 7;
    int koff[2];
#pragma unroll
    for (int kk = 0; kk < 2; kk++) koff[kk] = ((lq + 4 * kk) ^ sxr) * 8;
    const int arow0 = wm * 8192 + lane16 * 64;   // wave's A rows: wm*128+..
    const int brow0 = wn * 4096 + lane16 * 64;   // wave's B rows: wn*64+..

    f32x4_t acc[8][4];
#pragma unroll
    for (int i = 0; i < 8; i++)
#pragma unroll
      for (int j = 0; j < 4; j++) acc[i][j] = (f32x4_t){0.f, 0.f, 0.f, 0.f};

    bf16x8_t af[4][2], bf01[2][2], bf23[2][2];

    __bf16* const A0 = As[0]; __bf16* const A1 = As[1];
    __bf16* const B0 = Bs[0]; __bf16* const B1 = Bs[1];

    // prologue: tiles 0,1 fully staged; tile0 landed before first reads
    STAGE_A(A0, 0); STAGE_B(B0, 0);
    STAGE_A(A1, 1); STAGE_B(B1, 1);
    VMW(8);
    BAR();

    for (int it = 0; it < 8; ++it) {
        const int pre = (it < 7);
        const int k2 = 2 * it + 2, k3 = 2 * it + 3;
        TILE(A0, B0, k2, pre)
        TILE(A1, B1, k3, pre)
    }

    // C/D layout (16x16x32): col = lane16, row = lq*4 + reg
    if (bn < M) {
        // modal half: store G as bf16 into slot front halves
#pragma unroll
        for (int i = 0; i < 8; i++) {
#pragma unroll
            for (int r = 0; r < 4; r++) {
                const int grow = bm + wm * 128 + i * 16 + lq * 4 + r;
                __bf16* dst = (__bf16*)(arena + ((size_t)grow << 14)) +
                              bn + wn * 64 + lane16;
#pragma unroll
                for (int j = 0; j < 4; j++)
                    dst[j * 16] = (__bf16)acc[i][j][r];
            }
        }
    } else {
        // negatives half: per-row cosine max via atomicMax
        float invn[4];
#pragma unroll
        for (int j = 0; j < 4; j++)
            invn[j] = inv_nn[(bn - M) + wn * 64 + j * 16 + lane16];
#pragma unroll
        for (int i = 0; i < 8; i++) {
#pragma unroll
            for (int r = 0; r < 4; r++) {
                float v = acc[i][0][r] * invn[0];
                v = fmaxf(v, acc[i][1][r] * invn[1]);
                v = fmaxf(v, acc[i][2][r] * invn[2]);
                v = fmaxf(v, acc[i][3][r] * invn[3]);
#pragma unroll
                for (int o = 8; o > 0; o >>= 1)
                    v = fmaxf(v, __shfl_xor(v, o, WAVE));
                if (lane16 == 0)
                    atomicMax(&negmax_u[bm + wm * 128 + i * 16 + lq * 4 + r],
                              enc_f(v));
            }
        }
    }
}

// ---------------- softmax with fp32 fix-up, coalesced layout ---------------
#define CUT 2.0f
#define MAXCAND 64

__global__ __launch_bounds__(256)
void softmax_fix_kernel(char* __restrict__ arena, const float* __restrict__ step,
                        const float* __restrict__ modal,
                        const float* __restrict__ ina, const float* __restrict__ inb,
                        float* __restrict__ perstep, float* __restrict__ wout,
                        float* __restrict__ attn) {
    const int row = blockIdx.x, tid = threadIdx.x;
    const int lane = tid & 63, wv = tid >> 6;

    __shared__ float srow_s[1024];
    __shared__ float red[8];
    __shared__ float bcast[2];
    __shared__ int   cand[MAXCAND];
    __shared__ float exact[MAXCAND];
    __shared__ int   cnt;

    if (tid == 0) cnt = 0;
    ((float4*)srow_s)[tid] = ((const float4*)(step + (size_t)row * 1024))[tid];

    const __bf16* gb = (const __bf16*)(arena + ((size_t)row << 14));
    float vals[16];
    float invn[16];
#pragma unroll
    for (int g = 0; g < 4; g++) {
        const bf16x4_t v = *(const bf16x4_t*)(gb + g * 1024 + tid * 4);
        const float4 x = *(const float4*)(inb + g * 1024 + tid * 4);
        vals[g * 4 + 0] = (float)v[0]; vals[g * 4 + 1] = (float)v[1];
        vals[g * 4 + 2] = (float)v[2]; vals[g * 4 + 3] = (float)v[3];
        invn[g * 4 + 0] = x.x; invn[g * 4 + 1] = x.y;
        invn[g * 4 + 2] = x.z; invn[g * 4 + 3] = x.w;
    }

    float dmax = -3.4e38f;
#pragma unroll
    for (int j = 0; j < 16; j++) dmax = fmaxf(dmax, vals[j]);
    float wm = wave_reduce_max(dmax);
    if (lane == 0) red[wv] = wm;
    __syncthreads();   // also covers cnt=0 and srow_s
    if (tid == 0) bcast[0] = fmaxf(fmaxf(red[0], red[1]), fmaxf(red[2], red[3]));
    __syncthreads();
    const float m0 = bcast[0];

    const float thr = m0 - CUT;
#pragma unroll
    for (int g = 0; g < 4; g++)
#pragma unroll
        for (int u = 0; u < 4; u++) {
            if (vals[g * 4 + u] >= thr) {
                const int pos = atomicAdd(&cnt, 1);
                if (pos < MAXCAND) cand[pos] = g * 1024 + tid * 4 + u;
            }
        }
    __syncthreads();
    const int nc = min(cnt, MAXCAND);

    // exact fp32 dots, one candidate per wave
    for (int i = wv; i < nc; i += 4) {
        const float* mrow = modal + (size_t)cand[i] * 1024;
        float p = 0.0f;
#pragma unroll
        for (int q = 0; q < 16; q++) {
            const int idx = lane + q * 64;
            p = fmaf(srow_s[idx], mrow[idx], p);
        }
        p = wave_reduce_sum(p);
        if (lane == 0) exact[i] = p;
    }
    __syncthreads();

    for (int i = 0; i < nc; i++) {
        const int c = cand[i];
        if (((c & 1023) >> 2) == tid) vals[(c >> 10) * 4 + (c & 3)] = exact[i];
    }

    float dmax2 = -3.4e38f, cmax = -3.4e38f;
#pragma unroll
    for (int j = 0; j < 16; j++) {
        dmax2 = fmaxf(dmax2, vals[j]);
        cmax = fmaxf(cmax, vals[j] * invn[j]);
    }
    float wg = wave_reduce_max(dmax2);
    float wc = wave_reduce_max(cmax);
    if (lane == 0) { red[wv] = wg; red[4 + wv] = wc; }
    __syncthreads();
    if (tid == 0) {
        bcast[0] = fmaxf(fmaxf(red[0], red[1]), fmaxf(red[2], red[3]));
        bcast[1] = fmaxf(fmaxf(red[4], red[5]), fmaxf(red[6], red[7]));
    }
    __syncthreads();
    const float invT = 1.0f / 0.07f;
    const float mlog = bcast[0] * invT;
    const float cmaxAll = bcast[1];

    float evals[16];
    float lsum = 0.0f;
#pragma unroll
    for (int j = 0; j < 16; j++) {
        const float e = __expf(vals[j] * invT - mlog);
        evals[j] = e;
        lsum += e;
    }
    lsum = wave_reduce_sum(lsum);
    __syncthreads();
    if (lane == 0) red[wv] = lsum;
    __syncthreads();
    if (tid == 0) bcast[0] = red[0] + red[1] + red[2] + red[3];
    __syncthreads();
    const float invZ = 1.0f / bcast[0];

    float* arow = attn + (size_t)row * 4096;
    float wacc = 0.0f;
#pragma unroll
    for (int g = 0; g < 4; g++) {
        float4 o;
        const float a0 = evals[g * 4 + 0] * invZ, a1 = evals[g * 4 + 1] * invZ;
        const float a2 = evals[g * 4 + 2] * invZ, a3 = evals[g * 4 + 3] * invZ;
        o.x = a0; o.y = a1; o.z = a2; o.w = a3;
        *(float4*)(arow + g * 1024 + tid * 4) = o;
        wacc += a0 * vals[g * 4 + 0] * invn[g * 4 + 0];
        wacc += a1 * vals[g * 4 + 1] * invn[g * 4 + 1];
        wacc += a2 * vals[g * 4 + 2] * invn[g * 4 + 2];
        wacc += a3 * vals[g * 4 + 3] * invn[g * 4 + 3];
    }
    wacc = wave_reduce_sum(wacc);
    __syncthreads();
    if (lane == 0) red[wv] = wacc;
    __syncthreads();
    if (tid == 0) {
        const float inv_na = ina[row];
        perstep[row] = cmaxAll * inv_na;
        wout[row] = (red[0] + red[1] + red[2] + red[3]) * inv_na;
    }
}

// ---------------- finalize scalars -----------------------------------------
__global__ __launch_bounds__(1024)
void finalize_kernel(const float* __restrict__ perstep, const float* __restrict__ w,
                     const unsigned* __restrict__ negmax_u,
                     const float* __restrict__ ina, float* __restrict__ out,
                     int N, size_t NM) {
    float s_a = 0.0f, s_w = 0.0f, s_n = 0.0f, mn = 3.4e38f;
    for (int i = threadIdx.x; i < N; i += 1024) {
        const float p = perstep[i];
        s_a += p;
        s_w += w[i];
        s_n += dec_f(negmax_u[i]) * ina[i];
        mn = fminf(mn, p);
    }
    s_a = wave_reduce_sum(s_a);
    s_w = wave_reduce_sum(s_w);
    s_n = wave_reduce_sum(s_n);
    mn  = wave_reduce_min(mn);
    __shared__ float ra[16], rw[16], rn[16], rm[16];
    const int lane = threadIdx.x & 63, wv = threadIdx.x >> 6;
    if (lane == 0) { ra[wv] = s_a; rw[wv] = s_w; rn[wv] = s_n; rm[wv] = mn; }
    __syncthreads();
    if (threadIdx.x == 0) {
        float ta = 0, tw = 0, tn = 0, tm = 3.4e38f;
#pragma unroll
        for (int i = 0; i < 16; i++) {
            ta += ra[i]; tw += rw[i]; tn += rn[i]; tm = fminf(tm, rm[i]);
        }
        const float inv = 1.0f / (float)N;
        const float alignment = ta * inv;
        const float weighted  = tw * inv;
        const float neg       = tn * inv;
        const float contrast  = alignment - neg;
        const float margin    = fmaxf(contrast - 0.2f, 0.0f);
        const float overall   = 0.7f * weighted + 0.3f * contrast;
        out[0] = alignment;
        out[1] = weighted;
        float* p = out + 2 + NM;
        p[0] = contrast;
        p[1] = margin;
        p[2] = alignment;   // positive_alignment
        p[3] = neg;
        p[4 + N] = tm;      // min_step_coherence
        p[5 + N] = overall;
    }
}

// ---------------------------------------------------------------------------
extern "C" void kernel_launch(void* const* d_in, const int* in_sizes, int n_in,
                              void* d_out, int out_size, void* d_ws, size_t ws_size,
                              hipStream_t stream) {
    const float* step  = (const float*)d_in[0];
    const float* modal = (const float*)d_in[1];
    const float* negs  = (const float*)d_in[2];
    float* out = (float*)d_out;

    const int K = 1024;
    const int N = in_sizes[0] / K;   // 8192
    const int M = in_sizes[1] / K;   // 4096
    const size_t NM = (size_t)N * (size_t)M;

    float* ina        = (float*)d_ws;          // N
    float* inb        = ina + N;               // M
    float* inn        = inb + M;               // M
    unsigned* negmax  = (unsigned*)(inn + M);  // N
    float* wsum       = (float*)(negmax + N);  // N

    char* arena    = (char*)d_out + 16;
    float* attn    = out + 2;
    float* perstep = out + 2 + NM + 4;

    // 1. convert inputs to bf16 chunks + inverse norms + init atomics
    convert_norms_kernel<<<(N + 2 * M) / 4, 256, 0, stream>>>(
        step, modal, negs, arena, ina, inb, inn, negmax, N, M);

    // 2. fused GEMM, 256^2 8-phase (T1+T2+T3+T4+T5)
    const int nblocks = (N >> 8) * ((2 * M) >> 8);   // 32 x 32 = 1024
    gemm_fused_kernel<<<nblocks, 512, 0, stream>>>(arena, N, M, inn, negmax);

    // 3. softmax + exact fp32 fix-up, writes fp32 attention + per-row outs
    softmax_fix_kernel<<<N, 256, 0, stream>>>(arena, step, modal, ina, inb,
                                              perstep, wsum, attn);

    // 4. scalars
    finalize_kernel<<<1, 1024, 0, stream>>>(perstep, wsum, negmax, ina, out, N, NM);
}

// Round 2
// 360.894 us; speedup vs baseline: 1.0557x; 1.0554x over previous
//
#include <hip/hip_runtime.h>
#include <cmath>

// ---------------------------------------------------------------------------
// Round 13: keep round-12's 256^2 8-phase GEMM schedule EXACTLY; fix the
// block->XCD mapping that caused 360MB L2-fill (round-12 regression):
//   xcd = lin & 7 (round-robin), j = lin >> 3 (per-XCD time order).
//   XCD x owns A-panels 4x..4x+3 (2MB, L2-resident for the whole kernel);
//   per round of 32 concurrent blocks (1 block/CU, 32 CU/XCD): 4bm x 8bn ->
//   8 B-panels shared by 4 blocks each, K-synchronized (window ~1MB).
//   Per-XCD L2 fill ~= 2MB A + 16MB B streamed -> device FETCH ~150-200MB
//   (vs 360MB), so staging no longer outruns L3 bandwidth.
// Arena (inside attention output region): slot r (16 KB) =
//   [ G-bf16 row r : 8 KB | input bf16 chunks 4r..4r+3 : 8 KB ]
// chunk order: 0..N-1 step, N..N+M-1 modal, N+M..N+2M-1 negs.
// ---------------------------------------------------------------------------

#define WAVE 64

typedef __bf16 bf16x8_t __attribute__((ext_vector_type(8)));
typedef __bf16 bf16x4_t __attribute__((ext_vector_type(4)));
typedef float f32x4_t __attribute__((ext_vector_type(4)));

__device__ __forceinline__ float wave_reduce_sum(float v) {
#pragma unroll
    for (int o = 32; o > 0; o >>= 1) v += __shfl_down(v, o, WAVE);
    return v;
}
__device__ __forceinline__ float wave_reduce_max(float v) {
#pragma unroll
    for (int o = 32; o > 0; o >>= 1) v = fmaxf(v, __shfl_down(v, o, WAVE));
    return v;
}
__device__ __forceinline__ float wave_reduce_min(float v) {
#pragma unroll
    for (int o = 32; o > 0; o >>= 1) v = fminf(v, __shfl_down(v, o, WAVE));
    return v;
}

// monotone float <-> uint map for atomicMax on floats of any sign
__device__ __forceinline__ unsigned enc_f(float f) {
    unsigned u = __float_as_uint(f);
    return (u & 0x80000000u) ? ~u : (u | 0x80000000u);
}
__device__ __forceinline__ float dec_f(unsigned e) {
    unsigned u = (e & 0x80000000u) ? (e & 0x7fffffffu) : ~e;
    return __uint_as_float(u);
}

// ---------------- convert fp32 -> bf16 chunks + inverse norms --------------
// one row per WAVE (4 rows/block), no block barriers.
__global__ __launch_bounds__(256)
void convert_norms_kernel(const float* __restrict__ step,
                          const float* __restrict__ modal,
                          const float* __restrict__ negs,
                          char* __restrict__ arena,
                          float* __restrict__ ina, float* __restrict__ inb,
                          float* __restrict__ inn,
                          unsigned* __restrict__ negmax_u, int N, int M) {
    const int tid = threadIdx.x, lane = tid & 63, wv = tid >> 6;
    const int b = blockIdx.x * 4 + wv;
    const float* src;
    if (b < N)          src = step  + (size_t)b * 1024;
    else if (b < N + M) src = modal + (size_t)(b - N) * 1024;
    else                src = negs  + (size_t)(b - N - M) * 1024;

    char* cb = arena + (((size_t)(b >> 2)) << 14) + ((size_t)(b & 3) << 11) + 8192;
    float s = 0.0f;
#pragma unroll
    for (int q = 0; q < 4; q++) {
        const int idx = lane + q * 64;
        const float4 v = ((const float4*)src)[idx];
        bf16x4_t o;
        o[0] = (__bf16)v.x; o[1] = (__bf16)v.y;
        o[2] = (__bf16)v.z; o[3] = (__bf16)v.w;
        *(bf16x4_t*)(cb + (size_t)idx * 8) = o;
        s += v.x * v.x + v.y * v.y + v.z * v.z + v.w * v.w;
    }
    s = wave_reduce_sum(s);
    if (lane == 0) {
        const float inv = 1.0f / fmaxf(sqrtf(s), 1e-8f);
        if (b < N)          { ina[b] = inv; negmax_u[b] = 0u; }
        else if (b < N + M) inb[b - N] = inv;
        else                inn[b - N - M] = inv;
    }
}

// ---------------- fused bf16 MFMA GEMM, 256^2 8-phase ----------------------
#define GLD16(g, l)                                                       \
    __builtin_amdgcn_global_load_lds(                                     \
        (const __attribute__((address_space(1))) void*)(g),               \
        (__attribute__((address_space(3))) void*)(l), 16, 0, 0)

#define BAR()   asm volatile("s_barrier" ::: "memory")
#define LGKM0() asm volatile("s_waitcnt lgkmcnt(0)" ::: "memory")
#define VMW(n)  asm volatile("s_waitcnt vmcnt(" #n ")" ::: "memory")

#define STAGE_A(Ab, kt)                                                   \
    _Pragma("unroll")                                                     \
    for (int h = 0; h < 2; h++)                                           \
    _Pragma("unroll")                                                     \
      for (int c = 0; c < 2; c++)                                         \
        GLD16(arena + srcA[h][c] + (size_t)(kt) * 128,                    \
              (Ab) + h * 8192 + c * 4096 + w * 512);

#define STAGE_B(Bb, kt)                                                   \
    _Pragma("unroll")                                                     \
    for (int h = 0; h < 2; h++)                                           \
    _Pragma("unroll")                                                     \
      for (int c = 0; c < 2; c++)                                         \
        GLD16(arena + srcB[h][c] + (size_t)(kt) * 128,                    \
              (Bb) + h * 8192 + c * 4096 + w * 512);

#define READ_A(g, Ab)                                                     \
    _Pragma("unroll")                                                     \
    for (int ii = 0; ii < 4; ii++)                                        \
    _Pragma("unroll")                                                     \
      for (int kk = 0; kk < 2; kk++)                                      \
        af[ii][kk] = *(const bf16x8_t*)&(Ab)[arow0 + (g) * 4096 +         \
                                             ii * 1024 + koff[kk]];

#define READ_B(j0, dst, Bb)                                               \
    _Pragma("unroll")                                                     \
    for (int jj = 0; jj < 2; jj++)                                        \
    _Pragma("unroll")                                                     \
      for (int kk = 0; kk < 2; kk++)                                      \
        dst[jj][kk] = *(const bf16x8_t*)&(Bb)[brow0 + ((j0) + jj) * 1024 +\
                                              koff[kk]];

#define MFMA_Q(i0, j0, bsrc)                                              \
    __builtin_amdgcn_s_setprio(1);                                        \
    _Pragma("unroll")                                                     \
    for (int kk = 0; kk < 2; kk++)                                        \
    _Pragma("unroll")                                                     \
      for (int ii = 0; ii < 4; ii++)                                      \
      _Pragma("unroll")                                                   \
        for (int jj = 0; jj < 2; jj++)                                    \
          acc[(i0) + ii][(j0) + jj] =                                     \
              __builtin_amdgcn_mfma_f32_16x16x32_bf16(                    \
                  af[ii][kk], bsrc[jj][kk], acc[(i0) + ii][(j0) + jj],    \
                  0, 0, 0);                                               \
    __builtin_amdgcn_s_setprio(0);

// one K-tile = 4 phases, 16 MFMA each; counted vmcnt once at phase 4
#define TILE(Ab, Bb, ktpre, pre)                                          \
    /* phase 1 */                                                         \
    READ_A(0, Ab);                                                        \
    READ_B(0, bf01, Bb);                                                  \
    BAR(); LGKM0();                                                       \
    MFMA_Q(0, 0, bf01);                                                   \
    BAR();                                                                \
    /* phase 2 */                                                         \
    READ_B(2, bf23, Bb);                                                  \
    BAR(); LGKM0();                                                       \
    MFMA_Q(0, 2, bf23);                                                   \
    BAR();                                                                \
    /* phase 3: B slots of this buffer free (read ph1-2) -> stage next */ \
    READ_A(1, Ab);                                                        \
    if (pre) { STAGE_B(Bb, ktpre); }                                      \
    BAR(); LGKM0();                                                       \
    MFMA_Q(4, 0, bf01);                                                   \
    BAR();                                                                \
    /* phase 4: A slots free (read ph1,3) -> stage next; counted vmcnt */ \
    if (pre) { STAGE_A(Ab, ktpre); }                                      \
    BAR();                                                                \
    MFMA_Q(4, 2, bf23);                                                   \
    if (pre) { VMW(8); } else { VMW(0); }                                 \
    BAR();

__global__ __launch_bounds__(512, 2)
void gemm_fused_kernel(char* __restrict__ arena, int N, int M,
                       const float* __restrict__ inv_nn,
                       unsigned* __restrict__ negmax_u) {
    __shared__ __bf16 As[2][256 * 64];   // 2 x 32 KB
    __shared__ __bf16 Bs[2][256 * 64];   // 2 x 32 KB  (total 128 KB)

    // XCD-pinned A-stripe mapping (1 block/CU, 32 CU/XCD, round-robin disp):
    //   xcd = lin&7 owns A-panels 4*xcd..4*xcd+3 (2MB, resident all rounds)
    //   j = lin>>3: round r = j>>5 picks 8 B-panels; u = j&31: 4bm x 8bn
    const int lin = blockIdx.x;
    const int xcd = lin & 7;
    const int j   = lin >> 3;
    const int r   = j >> 5;
    const int u   = j & 31;
    const int bm = ((xcd << 2) + (u & 3)) << 8;
    const int bn = ((r << 3) + (u >> 2)) << 8;

    const int t = threadIdx.x, w = t >> 6, lane = t & 63;
    const int lane16 = lane & 15, lq = lane >> 4;
    const int wm = w >> 2, wn = w & 3;          // 2 M-waves x 4 N-waves

    // ---- staging source offsets (bytes from arena; xor-swizzled octet) ----
    const int l3 = lane >> 3, ol = lane & 7;
    const int og = ol ^ l3;                      // (grow&7)==l3 for all rows
    unsigned srcA[2][2], srcB[2][2];
#pragma unroll
    for (int h = 0; h < 2; h++)
#pragma unroll
      for (int c = 0; c < 2; c++) {
        const int ga = bm + h * 128 + c * 64 + w * 8 + l3;
        srcA[h][c] = ((unsigned)(ga >> 2) << 14) + ((unsigned)(ga & 3) << 11)
                     + 8192u + (unsigned)og * 16u;
        const int gb = N + bn + h * 128 + c * 64 + w * 8 + l3;
        srcB[h][c] = ((unsigned)(gb >> 2) << 14) + ((unsigned)(gb & 3) << 11)
                     + 8192u + (unsigned)og * 16u;
      }

    // ---- fragment read offsets (swizzled octet, elements) ----
    const int sxr = lane16 & 7;
    int koff[2];
#pragma unroll
    for (int kk = 0; kk < 2; kk++) koff[kk] = ((lq + 4 * kk) ^ sxr) * 8;
    const int arow0 = wm * 8192 + lane16 * 64;   // wave's A rows: wm*128+..
    const int brow0 = wn * 4096 + lane16 * 64;   // wave's B rows: wn*64+..

    f32x4_t acc[8][4];
#pragma unroll
    for (int i = 0; i < 8; i++)
#pragma unroll
      for (int j2 = 0; j2 < 4; j2++) acc[i][j2] = (f32x4_t){0.f, 0.f, 0.f, 0.f};

    bf16x8_t af[4][2], bf01[2][2], bf23[2][2];

    __bf16* const A0 = As[0]; __bf16* const A1 = As[1];
    __bf16* const B0 = Bs[0]; __bf16* const B1 = Bs[1];

    // prologue: tiles 0,1 fully staged; tile0 landed before first reads
    STAGE_A(A0, 0); STAGE_B(B0, 0);
    STAGE_A(A1, 1); STAGE_B(B1, 1);
    VMW(8);
    BAR();

    for (int it = 0; it < 8; ++it) {
        const int pre = (it < 7);
        const int k2 = 2 * it + 2, k3 = 2 * it + 3;
        TILE(A0, B0, k2, pre)
        TILE(A1, B1, k3, pre)
    }

    // C/D layout (16x16x32): col = lane16, row = lq*4 + reg
    if (bn < M) {
        // modal half: store G as bf16 into slot front halves
#pragma unroll
        for (int i = 0; i < 8; i++) {
#pragma unroll
            for (int rr = 0; rr < 4; rr++) {
                const int grow = bm + wm * 128 + i * 16 + lq * 4 + rr;
                __bf16* dst = (__bf16*)(arena + ((size_t)grow << 14)) +
                              bn + wn * 64 + lane16;
#pragma unroll
                for (int jj = 0; jj < 4; jj++)
                    dst[jj * 16] = (__bf16)acc[i][jj][rr];
            }
        }
    } else {
        // negatives half: per-row cosine max via atomicMax
        float invn[4];
#pragma unroll
        for (int jj = 0; jj < 4; jj++)
            invn[jj] = inv_nn[(bn - M) + wn * 64 + jj * 16 + lane16];
#pragma unroll
        for (int i = 0; i < 8; i++) {
#pragma unroll
            for (int rr = 0; rr < 4; rr++) {
                float v = acc[i][0][rr] * invn[0];
                v = fmaxf(v, acc[i][1][rr] * invn[1]);
                v = fmaxf(v, acc[i][2][rr] * invn[2]);
                v = fmaxf(v, acc[i][3][rr] * invn[3]);
#pragma unroll
                for (int o = 8; o > 0; o >>= 1)
                    v = fmaxf(v, __shfl_xor(v, o, WAVE));
                if (lane16 == 0)
                    atomicMax(&negmax_u[bm + wm * 128 + i * 16 + lq * 4 + rr],
                              enc_f(v));
            }
        }
    }
}

// ---------------- softmax with fp32 fix-up, coalesced layout ---------------
#define CUT 2.0f
#define MAXCAND 64

__global__ __launch_bounds__(256)
void softmax_fix_kernel(char* __restrict__ arena, const float* __restrict__ step,
                        const float* __restrict__ modal,
                        const float* __restrict__ ina, const float* __restrict__ inb,
                        float* __restrict__ perstep, float* __restrict__ wout,
                        float* __restrict__ attn) {
    const int row = blockIdx.x, tid = threadIdx.x;
    const int lane = tid & 63, wv = tid >> 6;

    __shared__ float srow_s[1024];
    __shared__ float red[8];
    __shared__ float bcast[2];
    __shared__ int   cand[MAXCAND];
    __shared__ float exact[MAXCAND];
    __shared__ int   cnt;

    if (tid == 0) cnt = 0;
    ((float4*)srow_s)[tid] = ((const float4*)(step + (size_t)row * 1024))[tid];

    const __bf16* gb = (const __bf16*)(arena + ((size_t)row << 14));
    float vals[16];
    float invn[16];
#pragma unroll
    for (int g = 0; g < 4; g++) {
        const bf16x4_t v = *(const bf16x4_t*)(gb + g * 1024 + tid * 4);
        const float4 x = *(const float4*)(inb + g * 1024 + tid * 4);
        vals[g * 4 + 0] = (float)v[0]; vals[g * 4 + 1] = (float)v[1];
        vals[g * 4 + 2] = (float)v[2]; vals[g * 4 + 3] = (float)v[3];
        invn[g * 4 + 0] = x.x; invn[g * 4 + 1] = x.y;
        invn[g * 4 + 2] = x.z; invn[g * 4 + 3] = x.w;
    }

    float dmax = -3.4e38f;
#pragma unroll
    for (int j = 0; j < 16; j++) dmax = fmaxf(dmax, vals[j]);
    float wm = wave_reduce_max(dmax);
    if (lane == 0) red[wv] = wm;
    __syncthreads();   // also covers cnt=0 and srow_s
    if (tid == 0) bcast[0] = fmaxf(fmaxf(red[0], red[1]), fmaxf(red[2], red[3]));
    __syncthreads();
    const float m0 = bcast[0];

    const float thr = m0 - CUT;
#pragma unroll
    for (int g = 0; g < 4; g++)
#pragma unroll
        for (int u = 0; u < 4; u++) {
            if (vals[g * 4 + u] >= thr) {
                const int pos = atomicAdd(&cnt, 1);
                if (pos < MAXCAND) cand[pos] = g * 1024 + tid * 4 + u;
            }
        }
    __syncthreads();
    const int nc = min(cnt, MAXCAND);

    // exact fp32 dots, one candidate per wave
    for (int i = wv; i < nc; i += 4) {
        const float* mrow = modal + (size_t)cand[i] * 1024;
        float p = 0.0f;
#pragma unroll
        for (int q = 0; q < 16; q++) {
            const int idx = lane + q * 64;
            p = fmaf(srow_s[idx], mrow[idx], p);
        }
        p = wave_reduce_sum(p);
        if (lane == 0) exact[i] = p;
    }
    __syncthreads();

    for (int i = 0; i < nc; i++) {
        const int c = cand[i];
        if (((c & 1023) >> 2) == tid) vals[(c >> 10) * 4 + (c & 3)] = exact[i];
    }

    float dmax2 = -3.4e38f, cmax = -3.4e38f;
#pragma unroll
    for (int j = 0; j < 16; j++) {
        dmax2 = fmaxf(dmax2, vals[j]);
        cmax = fmaxf(cmax, vals[j] * invn[j]);
    }
    float wg = wave_reduce_max(dmax2);
    float wc = wave_reduce_max(cmax);
    if (lane == 0) { red[wv] = wg; red[4 + wv] = wc; }
    __syncthreads();
    if (tid == 0) {
        bcast[0] = fmaxf(fmaxf(red[0], red[1]), fmaxf(red[2], red[3]));
        bcast[1] = fmaxf(fmaxf(red[4], red[5]), fmaxf(red[6], red[7]));
    }
    __syncthreads();
    const float invT = 1.0f / 0.07f;
    const float mlog = bcast[0] * invT;
    const float cmaxAll = bcast[1];

    float evals[16];
    float lsum = 0.0f;
#pragma unroll
    for (int j = 0; j < 16; j++) {
        const float e = __expf(vals[j] * invT - mlog);
        evals[j] = e;
        lsum += e;
    }
    lsum = wave_reduce_sum(lsum);
    __syncthreads();
    if (lane == 0) red[wv] = lsum;
    __syncthreads();
    if (tid == 0) bcast[0] = red[0] + red[1] + red[2] + red[3];
    __syncthreads();
    const float invZ = 1.0f / bcast[0];

    float* arow = attn + (size_t)row * 4096;
    float wacc = 0.0f;
#pragma unroll
    for (int g = 0; g < 4; g++) {
        float4 o;
        const float a0 = evals[g * 4 + 0] * invZ, a1 = evals[g * 4 + 1] * invZ;
        const float a2 = evals[g * 4 + 2] * invZ, a3 = evals[g * 4 + 3] * invZ;
        o.x = a0; o.y = a1; o.z = a2; o.w = a3;
        *(float4*)(arow + g * 1024 + tid * 4) = o;
        wacc += a0 * vals[g * 4 + 0] * invn[g * 4 + 0];
        wacc += a1 * vals[g * 4 + 1] * invn[g * 4 + 1];
        wacc += a2 * vals[g * 4 + 2] * invn[g * 4 + 2];
        wacc += a3 * vals[g * 4 + 3] * invn[g * 4 + 3];
    }
    wacc = wave_reduce_sum(wacc);
    __syncthreads();
    if (lane == 0) red[wv] = wacc;
    __syncthreads();
    if (tid == 0) {
        const float inv_na = ina[row];
        perstep[row] = cmaxAll * inv_na;
        wout[row] = (red[0] + red[1] + red[2] + red[3]) * inv_na;
    }
}

// ---------------- finalize scalars -----------------------------------------
__global__ __launch_bounds__(1024)
void finalize_kernel(const float* __restrict__ perstep, const float* __restrict__ w,
                     const unsigned* __restrict__ negmax_u,
                     const float* __restrict__ ina, float* __restrict__ out,
                     int N, size_t NM) {
    float s_a = 0.0f, s_w = 0.0f, s_n = 0.0f, mn = 3.4e38f;
    for (int i = threadIdx.x; i < N; i += 1024) {
        const float p = perstep[i];
        s_a += p;
        s_w += w[i];
        s_n += dec_f(negmax_u[i]) * ina[i];
        mn = fminf(mn, p);
    }
    s_a = wave_reduce_sum(s_a);
    s_w = wave_reduce_sum(s_w);
    s_n = wave_reduce_sum(s_n);
    mn  = wave_reduce_min(mn);
    __shared__ float ra[16], rw[16], rn[16], rm[16];
    const int lane = threadIdx.x & 63, wv = threadIdx.x >> 6;
    if (lane == 0) { ra[wv] = s_a; rw[wv] = s_w; rn[wv] = s_n; rm[wv] = mn; }
    __syncthreads();
    if (threadIdx.x == 0) {
        float ta = 0, tw = 0, tn = 0, tm = 3.4e38f;
#pragma unroll
        for (int i = 0; i < 16; i++) {
            ta += ra[i]; tw += rw[i]; tn += rn[i]; tm = fminf(tm, rm[i]);
        }
        const float inv = 1.0f / (float)N;
        const float alignment = ta * inv;
        const float weighted  = tw * inv;
        const float neg       = tn * inv;
        const float contrast  = alignment - neg;
        const float margin    = fmaxf(contrast - 0.2f, 0.0f);
        const float overall   = 0.7f * weighted + 0.3f * contrast;
        out[0] = alignment;
        out[1] = weighted;
        float* p = out + 2 + NM;
        p[0] = contrast;
        p[1] = margin;
        p[2] = alignment;   // positive_alignment
        p[3] = neg;
        p[4 + N] = tm;      // min_step_coherence
        p[5 + N] = overall;
    }
}

// ---------------------------------------------------------------------------
extern "C" void kernel_launch(void* const* d_in, const int* in_sizes, int n_in,
                              void* d_out, int out_size, void* d_ws, size_t ws_size,
                              hipStream_t stream) {
    const float* step  = (const float*)d_in[0];
    const float* modal = (const float*)d_in[1];
    const float* negs  = (const float*)d_in[2];
    float* out = (float*)d_out;

    const int K = 1024;
    const int N = in_sizes[0] / K;   // 8192
    const int M = in_sizes[1] / K;   // 4096
    const size_t NM = (size_t)N * (size_t)M;

    float* ina        = (float*)d_ws;          // N
    float* inb        = ina + N;               // M
    float* inn        = inb + M;               // M
    unsigned* negmax  = (unsigned*)(inn + M);  // N
    float* wsum       = (float*)(negmax + N);  // N

    char* arena    = (char*)d_out + 16;
    float* attn    = out + 2;
    float* perstep = out + 2 + NM + 4;

    // 1. convert inputs to bf16 chunks + inverse norms + init atomics
    convert_norms_kernel<<<(N + 2 * M) / 4, 256, 0, stream>>>(
        step, modal, negs, arena, ina, inb, inn, negmax, N, M);

    // 2. fused GEMM, 256^2 8-phase, XCD-pinned A-stripe mapping
    const int nblocks = (N >> 8) * ((2 * M) >> 8);   // 32 x 32 = 1024
    gemm_fused_kernel<<<nblocks, 512, 0, stream>>>(arena, N, M, inn, negmax);

    // 3. softmax + exact fp32 fix-up, writes fp32 attention + per-row outs
    softmax_fix_kernel<<<N, 256, 0, stream>>>(arena, step, modal, ina, inb,
                                              perstep, wsum, attn);

    // 4. scalars
    finalize_kernel<<<1, 1024, 0, stream>>>(perstep, wsum, negmax, ina, out, N, NM);
}

// Round 3
// 353.215 us; speedup vs baseline: 1.0787x; 1.0217x over previous
//
#include <hip/hip_runtime.h>
#include <cmath>

// ---------------------------------------------------------------------------
// Round 14: keep round-13's mapping (FETCH 104MB, good); restructure the tile
// schedule to overlap the LDS-read pipe with MFMA execution:
//   - reads for quadrant q+1 are issued immediately AFTER quadrant q's MFMA
//     cluster issues (cluster issues ~32cyc, executes ~620cyc -> LDS pipe
//     serves the reads under the matrix-pipe shadow)
//   - same register banks as round 13 (af[4][2] reused g0->g1, bf01, bf23):
//     WAR handled by compiler dep-tracking, ZERO extra VGPRs (252/256 budget)
//   - 3 barriers/tile (was 8): BAR_c (B-reads done -> STAGE_B safe),
//     BAR_e (A-reads done -> STAGE_A safe), BAR_g (VMW(8) -> cross-buffer
//     boundary reads safe). All other waits are lgkmcnt(0)/compiler-exact.
//   - staging k-schedule, xor-octet swizzle, epilogues: unchanged
// Arena (inside attention output region): slot r (16 KB) =
//   [ G-bf16 row r : 8 KB | input bf16 chunks 4r..4r+3 : 8 KB ]
// chunk order: 0..N-1 step, N..N+M-1 modal, N+M..N+2M-1 negs.
// ---------------------------------------------------------------------------

#define WAVE 64

typedef __bf16 bf16x8_t __attribute__((ext_vector_type(8)));
typedef __bf16 bf16x4_t __attribute__((ext_vector_type(4)));
typedef float f32x4_t __attribute__((ext_vector_type(4)));

__device__ __forceinline__ float wave_reduce_sum(float v) {
#pragma unroll
    for (int o = 32; o > 0; o >>= 1) v += __shfl_down(v, o, WAVE);
    return v;
}
__device__ __forceinline__ float wave_reduce_max(float v) {
#pragma unroll
    for (int o = 32; o > 0; o >>= 1) v = fmaxf(v, __shfl_down(v, o, WAVE));
    return v;
}
__device__ __forceinline__ float wave_reduce_min(float v) {
#pragma unroll
    for (int o = 32; o > 0; o >>= 1) v = fminf(v, __shfl_down(v, o, WAVE));
    return v;
}

// monotone float <-> uint map for atomicMax on floats of any sign
__device__ __forceinline__ unsigned enc_f(float f) {
    unsigned u = __float_as_uint(f);
    return (u & 0x80000000u) ? ~u : (u | 0x80000000u);
}
__device__ __forceinline__ float dec_f(unsigned e) {
    unsigned u = (e & 0x80000000u) ? (e & 0x7fffffffu) : ~e;
    return __uint_as_float(u);
}

// ---------------- convert fp32 -> bf16 chunks + inverse norms --------------
// one row per WAVE (4 rows/block), no block barriers.
__global__ __launch_bounds__(256)
void convert_norms_kernel(const float* __restrict__ step,
                          const float* __restrict__ modal,
                          const float* __restrict__ negs,
                          char* __restrict__ arena,
                          float* __restrict__ ina, float* __restrict__ inb,
                          float* __restrict__ inn,
                          unsigned* __restrict__ negmax_u, int N, int M) {
    const int tid = threadIdx.x, lane = tid & 63, wv = tid >> 6;
    const int b = blockIdx.x * 4 + wv;
    const float* src;
    if (b < N)          src = step  + (size_t)b * 1024;
    else if (b < N + M) src = modal + (size_t)(b - N) * 1024;
    else                src = negs  + (size_t)(b - N - M) * 1024;

    char* cb = arena + (((size_t)(b >> 2)) << 14) + ((size_t)(b & 3) << 11) + 8192;
    float s = 0.0f;
#pragma unroll
    for (int q = 0; q < 4; q++) {
        const int idx = lane + q * 64;
        const float4 v = ((const float4*)src)[idx];
        bf16x4_t o;
        o[0] = (__bf16)v.x; o[1] = (__bf16)v.y;
        o[2] = (__bf16)v.z; o[3] = (__bf16)v.w;
        *(bf16x4_t*)(cb + (size_t)idx * 8) = o;
        s += v.x * v.x + v.y * v.y + v.z * v.z + v.w * v.w;
    }
    s = wave_reduce_sum(s);
    if (lane == 0) {
        const float inv = 1.0f / fmaxf(sqrtf(s), 1e-8f);
        if (b < N)          { ina[b] = inv; negmax_u[b] = 0u; }
        else if (b < N + M) inb[b - N] = inv;
        else                inn[b - N - M] = inv;
    }
}

// ---------------- fused bf16 MFMA GEMM, overlapped-pipe schedule -----------
#define GLD16(g, l)                                                       \
    __builtin_amdgcn_global_load_lds(                                     \
        (const __attribute__((address_space(1))) void*)(g),               \
        (__attribute__((address_space(3))) void*)(l), 16, 0, 0)

#define BAR()   asm volatile("s_barrier" ::: "memory")
#define LGKM0() asm volatile("s_waitcnt lgkmcnt(0)" ::: "memory")
#define VMW(n)  asm volatile("s_waitcnt vmcnt(" #n ")" ::: "memory")

#define STAGE_A(Ab, kt)                                                   \
    _Pragma("unroll")                                                     \
    for (int h = 0; h < 2; h++)                                           \
    _Pragma("unroll")                                                     \
      for (int c = 0; c < 2; c++)                                         \
        GLD16(arena + srcA[h][c] + (size_t)(kt) * 128,                    \
              (Ab) + h * 8192 + c * 4096 + w * 512);

#define STAGE_B(Bb, kt)                                                   \
    _Pragma("unroll")                                                     \
    for (int h = 0; h < 2; h++)                                           \
    _Pragma("unroll")                                                     \
      for (int c = 0; c < 2; c++)                                         \
        GLD16(arena + srcB[h][c] + (size_t)(kt) * 128,                    \
              (Bb) + h * 8192 + c * 4096 + w * 512);

#define READ_A(g, Ab)                                                     \
    _Pragma("unroll")                                                     \
    for (int ii = 0; ii < 4; ii++)                                        \
    _Pragma("unroll")                                                     \
      for (int kk = 0; kk < 2; kk++)                                      \
        af[ii][kk] = *(const bf16x8_t*)&(Ab)[arow0 + (g) * 4096 +         \
                                             ii * 1024 + koff[kk]];

#define READ_B(j0, dst, Bb)                                               \
    _Pragma("unroll")                                                     \
    for (int jj = 0; jj < 2; jj++)                                        \
    _Pragma("unroll")                                                     \
      for (int kk = 0; kk < 2; kk++)                                      \
        dst[jj][kk] = *(const bf16x8_t*)&(Bb)[brow0 + ((j0) + jj) * 1024 +\
                                              koff[kk]];

#define READ_B01(Bb) READ_B(0, bf01, Bb)
#define READ_B23(Bb) READ_B(2, bf23, Bb)

#define MFMA_Q(i0, j0, bsrc)                                              \
    __builtin_amdgcn_s_setprio(1);                                        \
    _Pragma("unroll")                                                     \
    for (int kk = 0; kk < 2; kk++)                                        \
    _Pragma("unroll")                                                     \
      for (int ii = 0; ii < 4; ii++)                                      \
      _Pragma("unroll")                                                   \
        for (int jj = 0; jj < 2; jj++)                                    \
          acc[(i0) + ii][(j0) + jj] =                                     \
              __builtin_amdgcn_mfma_f32_16x16x32_bf16(                    \
                  af[ii][kk], bsrc[jj][kk], acc[(i0) + ii][(j0) + jj],    \
                  0, 0, 0);                                               \
    __builtin_amdgcn_s_setprio(0);

// one K-tile: 4 MFMA quadrants; reads for quadrant q+1 issued right after
// quadrant q's cluster (LDS pipe runs under matrix-pipe execution shadow).
// 3 barriers/tile: BAR_c (B-reads done), BAR_e (A-reads done), BAR_g (vmcnt).
#define TILE(Ac, Bc, An, Bn, ktpre, pre, rd)                              \
    LGKM0();               /* af_g0 + bf01 (boundary reads) ready */      \
    MFMA_Q(0, 0, bf01);                                                   \
    READ_B23(Bc);          /* 4 reads under MFMA1 exec */                 \
    LGKM0();                                                              \
    MFMA_Q(0, 2, bf23);                                                   \
    READ_A(1, Ac);         /* 8 reads under MFMA2 exec (af bank reuse) */ \
    BAR();                 /* BAR_c: all waves' B-reads complete */       \
    if (pre) { STAGE_B(Bc, ktpre); }                                      \
    LGKM0();               /* af_g1 ready */                              \
    MFMA_Q(4, 0, bf01);                                                   \
    BAR();                 /* BAR_e: all waves' A-reads complete */       \
    if (pre) { STAGE_A(Ac, ktpre); }                                      \
    MFMA_Q(4, 2, bf23);                                                   \
    if (rd) {                                                             \
        if (pre) { VMW(8); } else { VMW(0); }                             \
        BAR();             /* BAR_g: next-buffer stages landed */         \
        READ_A(0, An);     /* 12 boundary reads under MFMA4 drain */      \
        READ_B01(Bn);                                                     \
    }

__global__ __launch_bounds__(512, 2)
void gemm_fused_kernel(char* __restrict__ arena, int N, int M,
                       const float* __restrict__ inv_nn,
                       unsigned* __restrict__ negmax_u) {
    __shared__ __bf16 As[2][256 * 64];   // 2 x 32 KB
    __shared__ __bf16 Bs[2][256 * 64];   // 2 x 32 KB  (total 128 KB)

    // XCD-pinned A-stripe mapping (1 block/CU, 32 CU/XCD, round-robin disp):
    //   xcd = lin&7 owns A-panels 4*xcd..4*xcd+3 (2MB, resident all rounds)
    //   j = lin>>3: round r = j>>5 picks 8 B-panels; u = j&31: 4bm x 8bn
    const int lin = blockIdx.x;
    const int xcd = lin & 7;
    const int j   = lin >> 3;
    const int r   = j >> 5;
    const int u   = j & 31;
    const int bm = ((xcd << 2) + (u & 3)) << 8;
    const int bn = ((r << 3) + (u >> 2)) << 8;

    const int t = threadIdx.x, w = t >> 6, lane = t & 63;
    const int lane16 = lane & 15, lq = lane >> 4;
    const int wm = w >> 2, wn = w & 3;          // 2 M-waves x 4 N-waves

    // ---- staging source offsets (bytes from arena; xor-swizzled octet) ----
    const int l3 = lane >> 3, ol = lane & 7;
    const int og = ol ^ l3;                      // (grow&7)==l3 for all rows
    unsigned srcA[2][2], srcB[2][2];
#pragma unroll
    for (int h = 0; h < 2; h++)
#pragma unroll
      for (int c = 0; c < 2; c++) {
        const int ga = bm + h * 128 + c * 64 + w * 8 + l3;
        srcA[h][c] = ((unsigned)(ga >> 2) << 14) + ((unsigned)(ga & 3) << 11)
                     + 8192u + (unsigned)og * 16u;
        const int gb = N + bn + h * 128 + c * 64 + w * 8 + l3;
        srcB[h][c] = ((unsigned)(gb >> 2) << 14) + ((unsigned)(gb & 3) << 11)
                     + 8192u + (unsigned)og * 16u;
      }

    // ---- fragment read offsets (swizzled octet, elements) ----
    const int sxr = lane16 & 7;
    int koff[2];
#pragma unroll
    for (int kk = 0; kk < 2; kk++) koff[kk] = ((lq + 4 * kk) ^ sxr) * 8;
    const int arow0 = wm * 8192 + lane16 * 64;   // wave's A rows: wm*128+..
    const int brow0 = wn * 4096 + lane16 * 64;   // wave's B rows: wn*64+..

    f32x4_t acc[8][4];
#pragma unroll
    for (int i = 0; i < 8; i++)
#pragma unroll
      for (int j2 = 0; j2 < 4; j2++) acc[i][j2] = (f32x4_t){0.f, 0.f, 0.f, 0.f};

    bf16x8_t af[4][2], bf01[2][2], bf23[2][2];

    __bf16* const A0 = As[0]; __bf16* const A1 = As[1];
    __bf16* const B0 = Bs[0]; __bf16* const B1 = Bs[1];

    // prologue: tiles 0,1 fully staged; tile0 landed; boundary reads issued
    STAGE_A(A0, 0); STAGE_B(B0, 0);
    STAGE_A(A1, 1); STAGE_B(B1, 1);
    VMW(8);
    BAR();
    READ_A(0, A0);
    READ_B01(B0);

    for (int it = 0; it < 8; ++it) {
        const int pre = (it < 7);
        const int k2 = 2 * it + 2, k3 = 2 * it + 3;
        TILE(A0, B0, A1, B1, k2, pre, 1)
        TILE(A1, B1, A0, B0, k3, pre, pre)
    }

    // C/D layout (16x16x32): col = lane16, row = lq*4 + reg
    if (bn < M) {
        // modal half: store G as bf16 into slot front halves
#pragma unroll
        for (int i = 0; i < 8; i++) {
#pragma unroll
            for (int rr = 0; rr < 4; rr++) {
                const int grow = bm + wm * 128 + i * 16 + lq * 4 + rr;
                __bf16* dst = (__bf16*)(arena + ((size_t)grow << 14)) +
                              bn + wn * 64 + lane16;
#pragma unroll
                for (int jj = 0; jj < 4; jj++)
                    dst[jj * 16] = (__bf16)acc[i][jj][rr];
            }
        }
    } else {
        // negatives half: per-row cosine max via atomicMax
        float invn[4];
#pragma unroll
        for (int jj = 0; jj < 4; jj++)
            invn[jj] = inv_nn[(bn - M) + wn * 64 + jj * 16 + lane16];
#pragma unroll
        for (int i = 0; i < 8; i++) {
#pragma unroll
            for (int rr = 0; rr < 4; rr++) {
                float v = acc[i][0][rr] * invn[0];
                v = fmaxf(v, acc[i][1][rr] * invn[1]);
                v = fmaxf(v, acc[i][2][rr] * invn[2]);
                v = fmaxf(v, acc[i][3][rr] * invn[3]);
#pragma unroll
                for (int o = 8; o > 0; o >>= 1)
                    v = fmaxf(v, __shfl_xor(v, o, WAVE));
                if (lane16 == 0)
                    atomicMax(&negmax_u[bm + wm * 128 + i * 16 + lq * 4 + rr],
                              enc_f(v));
            }
        }
    }
}

// ---------------- softmax with fp32 fix-up, coalesced layout ---------------
#define CUT 2.0f
#define MAXCAND 64

__global__ __launch_bounds__(256)
void softmax_fix_kernel(char* __restrict__ arena, const float* __restrict__ step,
                        const float* __restrict__ modal,
                        const float* __restrict__ ina, const float* __restrict__ inb,
                        float* __restrict__ perstep, float* __restrict__ wout,
                        float* __restrict__ attn) {
    const int row = blockIdx.x, tid = threadIdx.x;
    const int lane = tid & 63, wv = tid >> 6;

    __shared__ float srow_s[1024];
    __shared__ float red[8];
    __shared__ float bcast[2];
    __shared__ int   cand[MAXCAND];
    __shared__ float exact[MAXCAND];
    __shared__ int   cnt;

    if (tid == 0) cnt = 0;
    ((float4*)srow_s)[tid] = ((const float4*)(step + (size_t)row * 1024))[tid];

    const __bf16* gb = (const __bf16*)(arena + ((size_t)row << 14));
    float vals[16];
    float invn[16];
#pragma unroll
    for (int g = 0; g < 4; g++) {
        const bf16x4_t v = *(const bf16x4_t*)(gb + g * 1024 + tid * 4);
        const float4 x = *(const float4*)(inb + g * 1024 + tid * 4);
        vals[g * 4 + 0] = (float)v[0]; vals[g * 4 + 1] = (float)v[1];
        vals[g * 4 + 2] = (float)v[2]; vals[g * 4 + 3] = (float)v[3];
        invn[g * 4 + 0] = x.x; invn[g * 4 + 1] = x.y;
        invn[g * 4 + 2] = x.z; invn[g * 4 + 3] = x.w;
    }

    float dmax = -3.4e38f;
#pragma unroll
    for (int j = 0; j < 16; j++) dmax = fmaxf(dmax, vals[j]);
    float wm = wave_reduce_max(dmax);
    if (lane == 0) red[wv] = wm;
    __syncthreads();   // also covers cnt=0 and srow_s
    if (tid == 0) bcast[0] = fmaxf(fmaxf(red[0], red[1]), fmaxf(red[2], red[3]));
    __syncthreads();
    const float m0 = bcast[0];

    const float thr = m0 - CUT;
#pragma unroll
    for (int g = 0; g < 4; g++)
#pragma unroll
        for (int u = 0; u < 4; u++) {
            if (vals[g * 4 + u] >= thr) {
                const int pos = atomicAdd(&cnt, 1);
                if (pos < MAXCAND) cand[pos] = g * 1024 + tid * 4 + u;
            }
        }
    __syncthreads();
    const int nc = min(cnt, MAXCAND);

    // exact fp32 dots, one candidate per wave
    for (int i = wv; i < nc; i += 4) {
        const float* mrow = modal + (size_t)cand[i] * 1024;
        float p = 0.0f;
#pragma unroll
        for (int q = 0; q < 16; q++) {
            const int idx = lane + q * 64;
            p = fmaf(srow_s[idx], mrow[idx], p);
        }
        p = wave_reduce_sum(p);
        if (lane == 0) exact[i] = p;
    }
    __syncthreads();

    for (int i = 0; i < nc; i++) {
        const int c = cand[i];
        if (((c & 1023) >> 2) == tid) vals[(c >> 10) * 4 + (c & 3)] = exact[i];
    }

    float dmax2 = -3.4e38f, cmax = -3.4e38f;
#pragma unroll
    for (int j = 0; j < 16; j++) {
        dmax2 = fmaxf(dmax2, vals[j]);
        cmax = fmaxf(cmax, vals[j] * invn[j]);
    }
    float wg = wave_reduce_max(dmax2);
    float wc = wave_reduce_max(cmax);
    if (lane == 0) { red[wv] = wg; red[4 + wv] = wc; }
    __syncthreads();
    if (tid == 0) {
        bcast[0] = fmaxf(fmaxf(red[0], red[1]), fmaxf(red[2], red[3]));
        bcast[1] = fmaxf(fmaxf(red[4], red[5]), fmaxf(red[6], red[7]));
    }
    __syncthreads();
    const float invT = 1.0f / 0.07f;
    const float mlog = bcast[0] * invT;
    const float cmaxAll = bcast[1];

    float evals[16];
    float lsum = 0.0f;
#pragma unroll
    for (int j = 0; j < 16; j++) {
        const float e = __expf(vals[j] * invT - mlog);
        evals[j] = e;
        lsum += e;
    }
    lsum = wave_reduce_sum(lsum);
    __syncthreads();
    if (lane == 0) red[wv] = lsum;
    __syncthreads();
    if (tid == 0) bcast[0] = red[0] + red[1] + red[2] + red[3];
    __syncthreads();
    const float invZ = 1.0f / bcast[0];

    float* arow = attn + (size_t)row * 4096;
    float wacc = 0.0f;
#pragma unroll
    for (int g = 0; g < 4; g++) {
        float4 o;
        const float a0 = evals[g * 4 + 0] * invZ, a1 = evals[g * 4 + 1] * invZ;
        const float a2 = evals[g * 4 + 2] * invZ, a3 = evals[g * 4 + 3] * invZ;
        o.x = a0; o.y = a1; o.z = a2; o.w = a3;
        *(float4*)(arow + g * 1024 + tid * 4) = o;
        wacc += a0 * vals[g * 4 + 0] * invn[g * 4 + 0];
        wacc += a1 * vals[g * 4 + 1] * invn[g * 4 + 1];
        wacc += a2 * vals[g * 4 + 2] * invn[g * 4 + 2];
        wacc += a3 * vals[g * 4 + 3] * invn[g * 4 + 3];
    }
    wacc = wave_reduce_sum(wacc);
    __syncthreads();
    if (lane == 0) red[wv] = wacc;
    __syncthreads();
    if (tid == 0) {
        const float inv_na = ina[row];
        perstep[row] = cmaxAll * inv_na;
        wout[row] = (red[0] + red[1] + red[2] + red[3]) * inv_na;
    }
}

// ---------------- finalize scalars -----------------------------------------
__global__ __launch_bounds__(1024)
void finalize_kernel(const float* __restrict__ perstep, const float* __restrict__ w,
                     const unsigned* __restrict__ negmax_u,
                     const float* __restrict__ ina, float* __restrict__ out,
                     int N, size_t NM) {
    float s_a = 0.0f, s_w = 0.0f, s_n = 0.0f, mn = 3.4e38f;
    for (int i = threadIdx.x; i < N; i += 1024) {
        const float p = perstep[i];
        s_a += p;
        s_w += w[i];
        s_n += dec_f(negmax_u[i]) * ina[i];
        mn = fminf(mn, p);
    }
    s_a = wave_reduce_sum(s_a);
    s_w = wave_reduce_sum(s_w);
    s_n = wave_reduce_sum(s_n);
    mn  = wave_reduce_min(mn);
    __shared__ float ra[16], rw[16], rn[16], rm[16];
    const int lane = threadIdx.x & 63, wv = threadIdx.x >> 6;
    if (lane == 0) { ra[wv] = s_a; rw[wv] = s_w; rn[wv] = s_n; rm[wv] = mn; }
    __syncthreads();
    if (threadIdx.x == 0) {
        float ta = 0, tw = 0, tn = 0, tm = 3.4e38f;
#pragma unroll
        for (int i = 0; i < 16; i++) {
            ta += ra[i]; tw += rw[i]; tn += rn[i]; tm = fminf(tm, rm[i]);
        }
        const float inv = 1.0f / (float)N;
        const float alignment = ta * inv;
        const float weighted  = tw * inv;
        const float neg       = tn * inv;
        const float contrast  = alignment - neg;
        const float margin    = fmaxf(contrast - 0.2f, 0.0f);
        const float overall   = 0.7f * weighted + 0.3f * contrast;
        out[0] = alignment;
        out[1] = weighted;
        float* p = out + 2 + NM;
        p[0] = contrast;
        p[1] = margin;
        p[2] = alignment;   // positive_alignment
        p[3] = neg;
        p[4 + N] = tm;      // min_step_coherence
        p[5 + N] = overall;
    }
}

// ---------------------------------------------------------------------------
extern "C" void kernel_launch(void* const* d_in, const int* in_sizes, int n_in,
                              void* d_out, int out_size, void* d_ws, size_t ws_size,
                              hipStream_t stream) {
    const float* step  = (const float*)d_in[0];
    const float* modal = (const float*)d_in[1];
    const float* negs  = (const float*)d_in[2];
    float* out = (float*)d_out;

    const int K = 1024;
    const int N = in_sizes[0] / K;   // 8192
    const int M = in_sizes[1] / K;   // 4096
    const size_t NM = (size_t)N * (size_t)M;

    float* ina        = (float*)d_ws;          // N
    float* inb        = ina + N;               // M
    float* inn        = inb + M;               // M
    unsigned* negmax  = (unsigned*)(inn + M);  // N
    float* wsum       = (float*)(negmax + N);  // N

    char* arena    = (char*)d_out + 16;
    float* attn    = out + 2;
    float* perstep = out + 2 + NM + 4;

    // 1. convert inputs to bf16 chunks + inverse norms + init atomics
    convert_norms_kernel<<<(N + 2 * M) / 4, 256, 0, stream>>>(
        step, modal, negs, arena, ina, inb, inn, negmax, N, M);

    // 2. fused GEMM, overlapped-pipe schedule, XCD-pinned A-stripe mapping
    const int nblocks = (N >> 8) * ((2 * M) >> 8);   // 32 x 32 = 1024
    gemm_fused_kernel<<<nblocks, 512, 0, stream>>>(arena, N, M, inn, negmax);

    // 3. softmax + exact fp32 fix-up, writes fp32 attention + per-row outs
    softmax_fix_kernel<<<N, 256, 0, stream>>>(arena, step, modal, ina, inb,
                                              perstep, wsum, attn);

    // 4. scalars
    finalize_kernel<<<1, 1024, 0, stream>>>(perstep, wsum, negmax, ina, out, N, NM);
}